// Round 9
// baseline (237.766 us; speedup 1.0000x reference)
//
#include <hip/hip_runtime.h>
#include <hip/hip_bf16.h>

// EMAQuantizer: z[32][512][32][32] fp32, embedding[1024][512] fp32.
// d_out fp32 concat: quantized [32][512][32][32] then indices [32][1024].
//
// Pipeline: prep_e (embedding -> hi/lo bf16 tile images in ws)
//           prep_z (z -> hi/lo bf16 tile images in d_out-as-scratch)
//           vq_gemm (global_load_lds DMA staging, 3-pass split-bf16 MFMA)
//           vq_reduce (combine 8 partials, gather, overwrite d_out)
#define CDIM 512
#define KDIM 1024
#define HW   1024
#define NPOS 32768
#define BM   128
#define BN   128
#define BK   32
#define NKS  16             // CDIM/BK
#define NNB  8              // KDIM/BN
#define PAY  8192           // ushorts per (tile,ks) payload: hi 4096 | lo 4096 (16KB)

typedef float  f32x16 __attribute__((ext_vector_type(16)));
typedef float  f4     __attribute__((ext_vector_type(4)));
typedef short  bf16x8 __attribute__((ext_vector_type(8)));
typedef unsigned int u32x4 __attribute__((ext_vector_type(4)));

static __device__ __forceinline__ unsigned short f2bf(float f) {
    __hip_bfloat16 h = __float2bfloat16(f);           // RNE
    union { __hip_bfloat16 h; unsigned short u; } cv; cv.h = h; return cv.u;
}
static __device__ __forceinline__ float bf2f(unsigned short u) {
    union { unsigned short u; __hip_bfloat16 h; } cv; cv.u = u; return __bfloat162float(cv.h);
}

// global (AS1) -> LDS (AS3) 16-byte DMA; dest = wave-uniform base + lane*16.
static __device__ __forceinline__ void gld16(const unsigned short* g, unsigned short* l) {
    __builtin_amdgcn_global_load_lds(
        (const __attribute__((address_space(1))) void*)g,
        (__attribute__((address_space(3))) void*)l,
        16, 0, 0);
}

// ---------------------------------------------------------------------------
// prep_e: embedding row k -> Bt payload images + enorm.
// Bt layout (ushort): [(nb*16+ks)] * PAY + h*4096 + slot*1024 + row*8
// grid: KDIM x 64.
// ---------------------------------------------------------------------------
__global__ __launch_bounds__(64) void prep_e(const float* __restrict__ e,
                                             unsigned short* __restrict__ Bt,
                                             float* __restrict__ enorm) {
    const int k  = blockIdx.x;
    const int t  = threadIdx.x;
    const int nb = k >> 7, row = k & 127;
    const int ks = t >> 2, slot = t & 3;

    const f4* src = (const f4*)(e + (size_t)k * CDIM + t * 8);
    const f4 a = src[0], b = src[1];
    const float v[8] = {a.x, a.y, a.z, a.w, b.x, b.y, b.z, b.w};

    unsigned int hw_[4], lw_[4];
    float ss = 0.0f;
    #pragma unroll
    for (int d = 0; d < 4; ++d) {
        const float v0 = v[2 * d], v1 = v[2 * d + 1];
        const unsigned short h0 = f2bf(v0), h1 = f2bf(v1);
        hw_[d] = (unsigned int)h0 | ((unsigned int)h1 << 16);
        lw_[d] = (unsigned int)f2bf(v0 - bf2f(h0)) |
                 ((unsigned int)f2bf(v1 - bf2f(h1)) << 16);
        ss += v0 * v0 + v1 * v1;
    }
    const size_t base = (size_t)(nb * 16 + ks) * PAY + slot * 1024 + row * 8;
    *(u32x4*)(Bt + base)        = u32x4{hw_[0], hw_[1], hw_[2], hw_[3]};
    *(u32x4*)(Bt + base + 4096) = u32x4{lw_[0], lw_[1], lw_[2], lw_[3]};

    #pragma unroll
    for (int o = 32; o > 0; o >>= 1) ss += __shfl_down(ss, o, 64);
    if (t == 0) enorm[k] = ss;
}

// ---------------------------------------------------------------------------
// prep_z: z -> Az payload images (in d_out scratch).
// 1024 blocks -> 4 blocks/CU, latency hidden by TLP.
// Block = (m-tile, ks-quad): 128 positions x 128 channels.
// Az layout: [(m*16+ks)] * PAY + h*4096 + slot*1024 + pos*8
// grid: 1024 x 256.
// ---------------------------------------------------------------------------
__global__ __launch_bounds__(256) void prep_z(const float* __restrict__ z,
                                              unsigned short* __restrict__ Az) {
    const int blk = blockIdx.x;
    const int m   = blk >> 2;            // m-tile (128 positions)
    const int q   = blk & 3;             // ks-quad (4 K-steps = 128 channels)
    const int t   = threadIdx.x;
    const int b   = m >> 3;
    const int hw0 = (m & 7) * 128;
    const int sp  = t & 127;             // position
    const int sh  = t >> 7;              // which ks of a pair

    const float* zbase = z + (size_t)b * CDIM * HW + hw0 + sp;

    #pragma unroll
    for (int it = 0; it < 2; ++it) {
        const int ksl = it * 2 + sh;     // 0..3 within quad
        const int ks  = q * 4 + ksl;
        const int cb  = ks * 32;
        float v[32];
        #pragma unroll
        for (int i = 0; i < 32; ++i) v[i] = zbase[(size_t)(cb + i) * HW];

        const size_t tbase = (size_t)(m * 16 + ks) * PAY + sp * 8;
        #pragma unroll
        for (int slot = 0; slot < 4; ++slot) {
            unsigned int hw_[4], lw_[4];
            #pragma unroll
            for (int d = 0; d < 4; ++d) {
                const float a0 = v[slot * 8 + 2 * d], a1 = v[slot * 8 + 2 * d + 1];
                const unsigned short h0 = f2bf(a0), h1 = f2bf(a1);
                hw_[d] = (unsigned int)h0 | ((unsigned int)h1 << 16);
                lw_[d] = (unsigned int)f2bf(a0 - bf2f(h0)) |
                         ((unsigned int)f2bf(a1 - bf2f(h1)) << 16);
            }
            *(u32x4*)(Az + tbase + slot * 1024)        = u32x4{hw_[0], hw_[1], hw_[2], hw_[3]};
            *(u32x4*)(Az + tbase + slot * 1024 + 4096) = u32x4{lw_[0], lw_[1], lw_[2], lw_[3]};
        }
    }
}

// ---------------------------------------------------------------------------
// vq_gemm: 128 pos x 128 codes, 3-pass split-bf16 MFMA. (unchanged, round 6)
// grid: 2048 x 256.
// ---------------------------------------------------------------------------
__global__ __launch_bounds__(256) void vq_gemm(const unsigned short* __restrict__ Az,
                                               const unsigned short* __restrict__ Bt,
                                               const float* __restrict__ enorm,
                                               float2* __restrict__ part) {
    __shared__ unsigned short lds[2][16384];
    __shared__ float lval[2][128];
    __shared__ int   lidx[2][128];

    const int bid = blockIdx.x;
    const int x = bid & 7, jj = bid >> 3;
    const int m  = x * 32 + (jj >> 3);
    const int nb = jj & 7;
    const int n0 = m * BM;

    const int t   = threadIdx.x;
    const int wid = t >> 6, l = t & 63;
    const int wr  = wid >> 1, wc = wid & 1;   // code-half, pos-half

    const unsigned short* asrc = Az + (size_t)m  * NKS * PAY;
    const unsigned short* bsrc = Bt + (size_t)nb * NKS * PAY;

    f32x16 acc[2][2];
    #pragma unroll
    for (int i = 0; i < 2; ++i)
        #pragma unroll
        for (int j = 0; j < 2; ++j) acc[i][j] = (f32x16)0.0f;

    // ---- prologue: stage ks=0 into buf 0 ---------------------------------
    #pragma unroll
    for (int i = 0; i < 4; ++i) {
        gld16(asrc + (size_t)(i * 256 + t) * 8, &lds[0][(i * 256 + t) * 8]);
        gld16(bsrc + (size_t)(i * 256 + t) * 8, &lds[0][8192 + (i * 256 + t) * 8]);
    }
    __syncthreads();

    const int pr = wc * 64 + (l & 31);
    const int cr = wr * 64 + (l & 31);
    const int lsel = l >> 5;

    #pragma unroll
    for (int ks = 0; ks < NKS; ++ks) {
        const int cb = ks & 1;
        if (ks + 1 < NKS) {
            const unsigned short* an = asrc + (size_t)(ks + 1) * PAY;
            const unsigned short* bn = bsrc + (size_t)(ks + 1) * PAY;
            #pragma unroll
            for (int i = 0; i < 4; ++i) {
                gld16(an + (size_t)(i * 256 + t) * 8, &lds[cb ^ 1][(i * 256 + t) * 8]);
                gld16(bn + (size_t)(i * 256 + t) * 8, &lds[cb ^ 1][8192 + (i * 256 + t) * 8]);
            }
        }
        __builtin_amdgcn_s_setprio(1);
        #pragma unroll
        for (int ksub = 0; ksub < 2; ++ksub) {
            const int so = ksub * 2 + lsel;
            const bf16x8 ch0 = *(const bf16x8*)&lds[cb][ 8192 + (so * 128 + cr) * 8];
            const bf16x8 ch1 = *(const bf16x8*)&lds[cb][ 8192 + (so * 128 + cr + 32) * 8];
            const bf16x8 cl0 = *(const bf16x8*)&lds[cb][12288 + (so * 128 + cr) * 8];
            const bf16x8 cl1 = *(const bf16x8*)&lds[cb][12288 + (so * 128 + cr + 32) * 8];
            const bf16x8 ph0 = *(const bf16x8*)&lds[cb][        (so * 128 + pr) * 8];
            const bf16x8 ph1 = *(const bf16x8*)&lds[cb][        (so * 128 + pr + 32) * 8];
            const bf16x8 pl0 = *(const bf16x8*)&lds[cb][ 4096 + (so * 128 + pr) * 8];
            const bf16x8 pl1 = *(const bf16x8*)&lds[cb][ 4096 + (so * 128 + pr + 32) * 8];
            acc[0][0] = __builtin_amdgcn_mfma_f32_32x32x16_bf16(ch0, ph0, acc[0][0], 0, 0, 0);
            acc[0][1] = __builtin_amdgcn_mfma_f32_32x32x16_bf16(ch0, ph1, acc[0][1], 0, 0, 0);
            acc[1][0] = __builtin_amdgcn_mfma_f32_32x32x16_bf16(ch1, ph0, acc[1][0], 0, 0, 0);
            acc[1][1] = __builtin_amdgcn_mfma_f32_32x32x16_bf16(ch1, ph1, acc[1][1], 0, 0, 0);
            acc[0][0] = __builtin_amdgcn_mfma_f32_32x32x16_bf16(ch0, pl0, acc[0][0], 0, 0, 0);
            acc[0][1] = __builtin_amdgcn_mfma_f32_32x32x16_bf16(ch0, pl1, acc[0][1], 0, 0, 0);
            acc[1][0] = __builtin_amdgcn_mfma_f32_32x32x16_bf16(ch1, pl0, acc[1][0], 0, 0, 0);
            acc[1][1] = __builtin_amdgcn_mfma_f32_32x32x16_bf16(ch1, pl1, acc[1][1], 0, 0, 0);
            acc[0][0] = __builtin_amdgcn_mfma_f32_32x32x16_bf16(cl0, ph0, acc[0][0], 0, 0, 0);
            acc[0][1] = __builtin_amdgcn_mfma_f32_32x32x16_bf16(cl0, ph1, acc[0][1], 0, 0, 0);
            acc[1][0] = __builtin_amdgcn_mfma_f32_32x32x16_bf16(cl1, ph0, acc[1][0], 0, 0, 0);
            acc[1][1] = __builtin_amdgcn_mfma_f32_32x32x16_bf16(cl1, ph1, acc[1][1], 0, 0, 0);
        }
        __builtin_amdgcn_s_setprio(0);
        __syncthreads();
    }

    // ---- argmin epilogue: dist = enorm[code] - 2*dot ---------------------
    // C/D layout (m74/m101): col = lane&31 (pos), row = (reg&3)+8*(reg>>2)+4*(lane>>5).
    const float* en = enorm + nb * 128 + wr * 64;
    #pragma unroll
    for (int pj = 0; pj < 2; ++pj) {
        float bv = 1e30f; int bi = 1 << 20;
        #pragma unroll
        for (int ci = 0; ci < 2; ++ci) {
            #pragma unroll
            for (int r = 0; r < 16; ++r) {
                const int code = ci * 32 + (r & 3) + 8 * (r >> 2) + 4 * lsel;
                const float val = en[code] - 2.0f * acc[ci][pj][r];
                if (val < bv || (val == bv && code < bi)) { bv = val; bi = code; }
            }
        }
        const float ov = __shfl_xor(bv, 32, 64);
        const int   oi = __shfl_xor(bi, 32, 64);
        if (ov < bv || (ov == bv && oi < bi)) { bv = ov; bi = oi; }
        if (l < 32) { lval[wr][wc * 64 + pj * 32 + l] = bv; lidx[wr][wc * 64 + pj * 32 + l] = bi; }
    }
    __syncthreads();

    if (t < 128) {
        const float v0 = lval[0][t]; const int i0 = lidx[0][t];
        const float v1 = lval[1][t]; const int i1 = lidx[1][t] + 64;
        float bv = v0; int bi = i0;
        if (v1 < bv || (v1 == bv && i1 < bi)) { bv = v1; bi = i1; }
        part[(size_t)(n0 + t) * 8 + nb] = make_float2(bv, (float)(nb * 128 + bi));
    }
}

// ---------------------------------------------------------------------------
// vq_reduce: combine 8 partials per position; write indices; gather rows and
// write quantized. 1024 blocks x 32 positions for 4 blocks/CU occupancy.
// Thread: 4 positions x 16 channels, 4x4 register transpose.
// grid: 1024 x 256.
// ---------------------------------------------------------------------------
__global__ __launch_bounds__(256) void vq_reduce(const float2* __restrict__ part,
                                                 const float* __restrict__ e,
                                                 float* __restrict__ out_q,
                                                 float* __restrict__ out_i) {
    __shared__ int bidx[32];
    const int t  = threadIdx.x;
    const int p0 = blockIdx.x * 32;

    if (t < 32) {
        const int n = p0 + t;
        const float2* pr = part + (size_t)n * 8;
        float bv = pr[0].x; int bi = (int)pr[0].y;
        #pragma unroll
        for (int nb = 1; nb < 8; ++nb) {
            const float2 c = pr[nb];
            const int ci = (int)c.y;
            if (c.x < bv || (c.x == bv && ci < bi)) { bv = c.x; bi = ci; }
        }
        bidx[t] = bi;
        out_i[n] = (float)bi;
    }
    __syncthreads();

    const int pq = t & 7;                // position quad (4 positions)
    const int cs = t >> 3;               // channel set (32 x 16 channels)
    const int n  = p0 + pq * 4;
    const int b  = n >> 10, hwp = n & 1023;

    const int r0 = bidx[pq * 4 + 0], r1 = bidx[pq * 4 + 1];
    const int r2 = bidx[pq * 4 + 2], r3 = bidx[pq * 4 + 3];
    const f4* e0 = (const f4*)(e + (size_t)r0 * CDIM) + cs * 4;
    const f4* e1 = (const f4*)(e + (size_t)r1 * CDIM) + cs * 4;
    const f4* e2 = (const f4*)(e + (size_t)r2 * CDIM) + cs * 4;
    const f4* e3 = (const f4*)(e + (size_t)r3 * CDIM) + cs * 4;
    float* oq = out_q + (size_t)b * CDIM * HW + hwp;

    #pragma unroll
    for (int qq = 0; qq < 4; ++qq) {
        const f4 a = e0[qq], bb = e1[qq], c = e2[qq], d = e3[qq];
        const int cbase = cs * 16 + qq * 4;
        *(f4*)(oq + (size_t)(cbase + 0) * HW) = f4{a.x, bb.x, c.x, d.x};
        *(f4*)(oq + (size_t)(cbase + 1) * HW) = f4{a.y, bb.y, c.y, d.y};
        *(f4*)(oq + (size_t)(cbase + 2) * HW) = f4{a.z, bb.z, c.z, d.z};
        *(f4*)(oq + (size_t)(cbase + 3) * HW) = f4{a.w, bb.w, c.w, d.w};
    }
}

// ---------------------------------------------------------------------------
extern "C" void kernel_launch(void* const* d_in, const int* in_sizes, int n_in,
                              void* d_out, int out_size, void* d_ws, size_t ws_size,
                              hipStream_t stream) {
    const float* z = (const float*)d_in[0];
    const float* e = (const float*)d_in[1];

    float* out_q = (float*)d_out;
    float* out_i = out_q + (out_size - NPOS);

    // z tile images live in the quantized-output region (64 MiB, dead until
    // vq_reduce fully overwrites it).
    unsigned short* Az = (unsigned short*)d_out;

    // ws (~4.2 MB): Bt 2MB | enorm 4KB | part 2MB
    unsigned short* Bt = (unsigned short*)d_ws;
    float*  enorm = (float*)((char*)d_ws + 2 * 1048576);
    float2* part  = (float2*)((char*)d_ws + 2 * 1048576 + 4096);

    prep_e<<<KDIM, 64, 0, stream>>>(e, Bt, enorm);
    prep_z<<<1024, 256, 0, stream>>>(z, Az);
    vq_gemm<<<(NPOS / BM) * NNB, 256, 0, stream>>>(Az, Bt, enorm, part);
    vq_reduce<<<NPOS / 32, 256, 0, stream>>>(part, e, out_q, out_i);
}